// Round 1
// baseline (80.127 us; speedup 1.0000x reference)
//
#include <hip/hip_runtime.h>

#define HIDDEN 128
#define N_NEG 25
#define MARGIN 4.0f
#define BATCH 4096

// One wave (64 lanes) computes the score of one (h, r, t) triple.
// Lane i owns dims [2i, 2i+1] -> float2 load = 8B/lane * 64 lanes = 512B,
// exactly one coalesced entity row per vector load instruction.
__device__ __forceinline__ float triple_score(
    const float* __restrict__ ent, const float* __restrict__ enttr,
    const float* __restrict__ rel, const float* __restrict__ reltr,
    int h, int t, int r, int lane)
{
    const size_t ho = (size_t)h * HIDDEN + (size_t)(lane * 2);
    const size_t to = (size_t)t * HIDDEN + (size_t)(lane * 2);
    const size_t ro = (size_t)r * HIDDEN + (size_t)(lane * 2);
    const float2 he = *reinterpret_cast<const float2*>(ent   + ho);
    const float2 ht = *reinterpret_cast<const float2*>(enttr + ho);
    const float2 te = *reinterpret_cast<const float2*>(ent   + to);
    const float2 tt = *reinterpret_cast<const float2*>(enttr + to);
    const float2 re = *reinterpret_cast<const float2*>(rel   + ro);
    const float2 rt = *reinterpret_cast<const float2*>(reltr + ro);

    // Per-lane partial dots for the two dynamic projections.
    float dh = he.x * ht.x + he.y * ht.y;   // dot(h_e, h_t) partial
    float dt = te.x * tt.x + te.y * tt.y;   // dot(t_e, t_t) partial

    // Wave-wide butterfly reduction over 64 lanes (both dots together).
    #pragma unroll
    for (int off = 32; off >= 1; off >>= 1) {
        dh += __shfl_xor(dh, off);
        dt += __shfl_xor(dt, off);
    }

    // s[d] = | h_e[d] - t_e[d] + r_e[d] + (dh - dt) * r_t[d] |
    const float diff = dh - dt;
    float s = fabsf(he.x - te.x + re.x + diff * rt.x)
            + fabsf(he.y - te.y + re.y + diff * rt.y);
    #pragma unroll
    for (int off = 32; off >= 1; off >>= 1) s += __shfl_xor(s, off);
    return s;  // all lanes hold the full sum over HIDDEN
}

__global__ void __launch_bounds__(256)
transd_loss_kernel(
    const float* __restrict__ ent,   const float* __restrict__ rel,
    const float* __restrict__ enttr, const float* __restrict__ reltr,
    const int* __restrict__ pos_h, const int* __restrict__ pos_t,
    const int* __restrict__ pos_r,
    const int* __restrict__ neg_h, const int* __restrict__ neg_t,
    const int* __restrict__ neg_r,
    float* __restrict__ out)
{
    const int b    = blockIdx.x;          // one block per batch item
    const int lane = threadIdx.x & 63;
    const int wid  = threadIdx.x >> 6;    // 4 waves/block

    __shared__ float sh_p;
    __shared__ float sh_n[4];

    float p = 0.0f;
    float n_partial = 0.0f;

    // Task 0 = positive triple; tasks 1..25 = negatives. Round-robin over waves.
    for (int task = wid; task < 1 + N_NEG; task += 4) {
        if (task == 0) {
            p = triple_score(ent, enttr, rel, reltr,
                             pos_h[b], pos_t[b], pos_r[b], lane);
        } else {
            const int j = b * N_NEG + (task - 1);
            n_partial += triple_score(ent, enttr, rel, reltr,
                                      neg_h[j], neg_t[j], neg_r[j], lane);
        }
    }

    if (lane == 0) {
        if (wid == 0) sh_p = p;           // task 0 always lands on wave 0
        sh_n[wid] = n_partial;
    }
    __syncthreads();

    if (threadIdx.x == 0) {
        const float n = (sh_n[0] + sh_n[1] + sh_n[2] + sh_n[3]) * (1.0f / N_NEG);
        const float loss = fmaxf(sh_p - n + MARGIN, 0.0f);
        atomicAdd(out, loss);             // one atomic per block
    }
}

__global__ void zero_out_kernel(float* out)
{
    if (threadIdx.x == 0 && blockIdx.x == 0) out[0] = 0.0f;
}

extern "C" void kernel_launch(void* const* d_in, const int* in_sizes, int n_in,
                              void* d_out, int out_size, void* d_ws, size_t ws_size,
                              hipStream_t stream)
{
    const float* ent   = (const float*)d_in[0];  // ent_embeddings [1M,128]
    const float* rel   = (const float*)d_in[1];  // rel_embeddings [1000,128]
    const float* enttr = (const float*)d_in[2];  // ent_transfer   [1M,128]
    const float* reltr = (const float*)d_in[3];  // rel_transfer   [1000,128]
    const int* pos_h = (const int*)d_in[4];
    const int* pos_t = (const int*)d_in[5];
    const int* pos_r = (const int*)d_in[6];
    const int* neg_h = (const int*)d_in[7];
    const int* neg_t = (const int*)d_in[8];
    const int* neg_r = (const int*)d_in[9];
    float* out = (float*)d_out;

    // Harness poisons d_out once and does not re-poison between replays:
    // zero it ourselves every call (deterministic).
    zero_out_kernel<<<1, 64, 0, stream>>>(out);

    transd_loss_kernel<<<BATCH, 256, 0, stream>>>(
        ent, rel, enttr, reltr,
        pos_h, pos_t, pos_r, neg_h, neg_t, neg_r, out);
}

// Round 2
// 49.977 us; speedup vs baseline: 1.6033x; 1.6033x over previous
//
#include <hip/hip_runtime.h>

#define HIDDEN 128
#define N_NEG 25
#define NTASK 26          // task 0 = positive, 1..25 = negatives
#define MARGIN 4.0f
#define BATCH 4096

// One wave (64 lanes) scores exactly one (h, r, t) triple.
// Lane i owns dims [2i, 2i+1] -> float2 = 8B/lane * 64 lanes = one 512B row
// per load instruction. 6 independent row loads in flight per wave, then two
// 6-step butterfly reductions. No __syncthreads, no inter-triple dependence.
__global__ void __launch_bounds__(256)
score_kernel(const float* __restrict__ ent,   const float* __restrict__ rel,
             const float* __restrict__ enttr, const float* __restrict__ reltr,
             const int* __restrict__ pos_h, const int* __restrict__ pos_t,
             const int* __restrict__ pos_r,
             const int* __restrict__ neg_h, const int* __restrict__ neg_t,
             const int* __restrict__ neg_r,
             float* __restrict__ scores)       // [NTASK][BATCH]
{
    const int lane = threadIdx.x & 63;
    const int w    = blockIdx.x * 4 + (threadIdx.x >> 6);  // global wave id
    const int b    = w / NTASK;
    const int task = w - b * NTASK;

    int h, t, r;
    if (task == 0) {
        h = pos_h[b]; t = pos_t[b]; r = pos_r[b];
    } else {
        const int j = b * N_NEG + (task - 1);
        h = neg_h[j]; t = neg_t[j]; r = neg_r[j];
    }

    const size_t ho = (size_t)h * HIDDEN + (size_t)(lane * 2);
    const size_t to = (size_t)t * HIDDEN + (size_t)(lane * 2);
    const size_t ro = (size_t)r * HIDDEN + (size_t)(lane * 2);
    const float2 he = *reinterpret_cast<const float2*>(ent   + ho);
    const float2 ht = *reinterpret_cast<const float2*>(enttr + ho);
    const float2 te = *reinterpret_cast<const float2*>(ent   + to);
    const float2 tt = *reinterpret_cast<const float2*>(enttr + to);
    const float2 re = *reinterpret_cast<const float2*>(rel   + ro);
    const float2 rt = *reinterpret_cast<const float2*>(reltr + ro);

    // Only diff = dot(h_e,h_t) - dot(t_e,t_t) is needed: reduce the
    // per-lane DIFFERENCE once (6 shuffle steps instead of 12).
    float diff = he.x * ht.x + he.y * ht.y - te.x * tt.x - te.y * tt.y;
    #pragma unroll
    for (int off = 32; off >= 1; off >>= 1) diff += __shfl_xor(diff, off);

    // s[d] = | h_e[d] - t_e[d] + r_e[d] + diff * r_t[d] |
    float s = fabsf(he.x - te.x + re.x + diff * rt.x)
            + fabsf(he.y - te.y + re.y + diff * rt.y);
    #pragma unroll
    for (int off = 32; off >= 1; off >>= 1) s += __shfl_xor(s, off);

    if (lane == 0) scores[(size_t)task * BATCH + b] = s;
}

// One thread per batch item: hinge(p - mean(n) + margin), then block-reduce
// and one atomicAdd per block (16 blocks total).
__global__ void __launch_bounds__(256)
loss_kernel(const float* __restrict__ scores, float* __restrict__ out)
{
    const int b = blockIdx.x * 256 + threadIdx.x;

    const float p = scores[b];                 // task 0 row
    float n = 0.0f;
    #pragma unroll
    for (int k = 1; k < NTASK; ++k) n += scores[(size_t)k * BATCH + b];

    float loss = fmaxf(p - n * (1.0f / N_NEG) + MARGIN, 0.0f);

    #pragma unroll
    for (int off = 32; off >= 1; off >>= 1) loss += __shfl_xor(loss, off);

    __shared__ float sh[4];
    if ((threadIdx.x & 63) == 0) sh[threadIdx.x >> 6] = loss;
    __syncthreads();
    if (threadIdx.x == 0)
        atomicAdd(out, sh[0] + sh[1] + sh[2] + sh[3]);
}

__global__ void zero_out_kernel(float* out)
{
    if (threadIdx.x == 0 && blockIdx.x == 0) out[0] = 0.0f;
}

extern "C" void kernel_launch(void* const* d_in, const int* in_sizes, int n_in,
                              void* d_out, int out_size, void* d_ws, size_t ws_size,
                              hipStream_t stream)
{
    const float* ent   = (const float*)d_in[0];  // ent_embeddings [1M,128]
    const float* rel   = (const float*)d_in[1];  // rel_embeddings [1000,128]
    const float* enttr = (const float*)d_in[2];  // ent_transfer   [1M,128]
    const float* reltr = (const float*)d_in[3];  // rel_transfer   [1000,128]
    const int* pos_h = (const int*)d_in[4];
    const int* pos_t = (const int*)d_in[5];
    const int* pos_r = (const int*)d_in[6];
    const int* neg_h = (const int*)d_in[7];
    const int* neg_t = (const int*)d_in[8];
    const int* neg_r = (const int*)d_in[9];
    float* out    = (float*)d_out;
    float* scores = (float*)d_ws;               // NTASK*BATCH floats = 426 KB

    zero_out_kernel<<<1, 64, 0, stream>>>(out);

    // 4096 * 26 triples, one wave each, 4 waves per block -> 26624 blocks.
    score_kernel<<<(BATCH * NTASK) / 4, 256, 0, stream>>>(
        ent, rel, enttr, reltr,
        pos_h, pos_t, pos_r, neg_h, neg_t, neg_r, scores);

    loss_kernel<<<BATCH / 256, 256, 0, stream>>>(scores, out);
}

// Round 3
// 48.409 us; speedup vs baseline: 1.6552x; 1.0324x over previous
//
#include <hip/hip_runtime.h>

#define HIDDEN 128
#define N_NEG 25
#define NTASK 26          // task 0 = positive, 1..25 = negatives
#define MARGIN 4.0f
#define BATCH 4096

// Score one (h, r, t) triple with one wave. Lane i owns dims [2i, 2i+1].
struct TripleRows {
    float2 he, ht, te, tt, re, rt;
};

__device__ __forceinline__ TripleRows load_rows(
    const float* __restrict__ ent,   const float* __restrict__ enttr,
    const float* __restrict__ rel,   const float* __restrict__ reltr,
    int h, int t, int r, int lane)
{
    const size_t ho = (size_t)h * HIDDEN + (size_t)(lane * 2);
    const size_t to = (size_t)t * HIDDEN + (size_t)(lane * 2);
    const size_t ro = (size_t)r * HIDDEN + (size_t)(lane * 2);
    TripleRows x;
    x.he = *reinterpret_cast<const float2*>(ent   + ho);
    x.ht = *reinterpret_cast<const float2*>(enttr + ho);
    x.te = *reinterpret_cast<const float2*>(ent   + to);
    x.tt = *reinterpret_cast<const float2*>(enttr + to);
    x.re = *reinterpret_cast<const float2*>(rel   + ro);
    x.rt = *reinterpret_cast<const float2*>(reltr + ro);
    return x;
}

// Each wave scores TWO triples: 12 independent row loads in flight, and the
// two shuffle-reduction chains interleave (ILP) instead of serializing.
__global__ void __launch_bounds__(256)
score_kernel(const float* __restrict__ ent,   const float* __restrict__ rel,
             const float* __restrict__ enttr, const float* __restrict__ reltr,
             const int* __restrict__ pos_h, const int* __restrict__ pos_t,
             const int* __restrict__ pos_r,
             const int* __restrict__ neg_h, const int* __restrict__ neg_t,
             const int* __restrict__ neg_r,
             float* __restrict__ scores)       // [NTASK][BATCH]
{
    const int lane = threadIdx.x & 63;
    const int w    = blockIdx.x * 4 + (threadIdx.x >> 6);  // global wave id
    const int tri0 = w * 2;                                // first triple
    const int tri1 = tri0 + 1;

    const int b0 = tri0 / NTASK, task0 = tri0 - b0 * NTASK;
    const int b1 = tri1 / NTASK, task1 = tri1 - b1 * NTASK;

    int h0, t0, r0, h1, t1, r1;
    if (task0 == 0) { h0 = pos_h[b0]; t0 = pos_t[b0]; r0 = pos_r[b0]; }
    else { const int j = b0 * N_NEG + (task0 - 1);
           h0 = neg_h[j]; t0 = neg_t[j]; r0 = neg_r[j]; }
    if (task1 == 0) { h1 = pos_h[b1]; t1 = pos_t[b1]; r1 = pos_r[b1]; }
    else { const int j = b1 * N_NEG + (task1 - 1);
           h1 = neg_h[j]; t1 = neg_t[j]; r1 = neg_r[j]; }

    // Issue all 12 row loads before any reduction (max MLP).
    const TripleRows a = load_rows(ent, enttr, rel, reltr, h0, t0, r0, lane);
    const TripleRows c = load_rows(ent, enttr, rel, reltr, h1, t1, r1, lane);

    // diff = dot(h_e,h_t) - dot(t_e,t_t): reduce the per-lane difference.
    float d0 = a.he.x * a.ht.x + a.he.y * a.ht.y
             - a.te.x * a.tt.x - a.te.y * a.tt.y;
    float d1 = c.he.x * c.ht.x + c.he.y * c.ht.y
             - c.te.x * c.tt.x - c.te.y * c.tt.y;
    #pragma unroll
    for (int off = 32; off >= 1; off >>= 1) {
        d0 += __shfl_xor(d0, off);
        d1 += __shfl_xor(d1, off);
    }

    // s[d] = | h_e[d] - t_e[d] + r_e[d] + diff * r_t[d] |
    float s0 = fabsf(a.he.x - a.te.x + a.re.x + d0 * a.rt.x)
             + fabsf(a.he.y - a.te.y + a.re.y + d0 * a.rt.y);
    float s1 = fabsf(c.he.x - c.te.x + c.re.x + d1 * c.rt.x)
             + fabsf(c.he.y - c.te.y + c.re.y + d1 * c.rt.y);
    #pragma unroll
    for (int off = 32; off >= 1; off >>= 1) {
        s0 += __shfl_xor(s0, off);
        s1 += __shfl_xor(s1, off);
    }

    if (lane == 0) {
        scores[(size_t)task0 * BATCH + b0] = s0;
        scores[(size_t)task1 * BATCH + b1] = s1;
    }
}

// One thread per batch item: hinge(p - mean(n) + margin), block-reduce,
// one atomicAdd per block (16 blocks total).
__global__ void __launch_bounds__(256)
loss_kernel(const float* __restrict__ scores, float* __restrict__ out)
{
    const int b = blockIdx.x * 256 + threadIdx.x;

    const float p = scores[b];                 // task 0 row
    float n = 0.0f;
    #pragma unroll
    for (int k = 1; k < NTASK; ++k) n += scores[(size_t)k * BATCH + b];

    float loss = fmaxf(p - n * (1.0f / N_NEG) + MARGIN, 0.0f);

    #pragma unroll
    for (int off = 32; off >= 1; off >>= 1) loss += __shfl_xor(loss, off);

    __shared__ float sh[4];
    if ((threadIdx.x & 63) == 0) sh[threadIdx.x >> 6] = loss;
    __syncthreads();
    if (threadIdx.x == 0)
        atomicAdd(out, sh[0] + sh[1] + sh[2] + sh[3]);
}

__global__ void zero_out_kernel(float* out)
{
    if (threadIdx.x == 0 && blockIdx.x == 0) out[0] = 0.0f;
}

extern "C" void kernel_launch(void* const* d_in, const int* in_sizes, int n_in,
                              void* d_out, int out_size, void* d_ws, size_t ws_size,
                              hipStream_t stream)
{
    const float* ent   = (const float*)d_in[0];  // ent_embeddings [1M,128]
    const float* rel   = (const float*)d_in[1];  // rel_embeddings [1000,128]
    const float* enttr = (const float*)d_in[2];  // ent_transfer   [1M,128]
    const float* reltr = (const float*)d_in[3];  // rel_transfer   [1000,128]
    const int* pos_h = (const int*)d_in[4];
    const int* pos_t = (const int*)d_in[5];
    const int* pos_r = (const int*)d_in[6];
    const int* neg_h = (const int*)d_in[7];
    const int* neg_t = (const int*)d_in[8];
    const int* neg_r = (const int*)d_in[9];
    float* out    = (float*)d_out;
    float* scores = (float*)d_ws;               // NTASK*BATCH floats = 426 KB

    zero_out_kernel<<<1, 64, 0, stream>>>(out);

    // 4096*26 triples, two per wave, 4 waves per block -> 13312 blocks.
    score_kernel<<<(BATCH * NTASK) / 8, 256, 0, stream>>>(
        ent, rel, enttr, reltr,
        pos_h, pos_t, pos_r, neg_h, neg_t, neg_r, scores);

    loss_kernel<<<BATCH / 256, 256, 0, stream>>>(scores, out);
}